// Round 3
// baseline (346.097 us; speedup 1.0000x reference)
//
#include <hip/hip_runtime.h>
#include <hip/hip_bf16.h>
#include <cstdint>

#define DI __device__ __forceinline__

typedef __attribute__((ext_vector_type(8))) short short8;
typedef __attribute__((ext_vector_type(4))) float f32x4;
typedef __attribute__((ext_vector_type(4))) int int4v;

DI f32x4 mfma16(short8 a, short8 b, f32x4 c) {
  return __builtin_amdgcn_mfma_f32_16x16x32_bf16(a, b, c, 0, 0, 0);
}

// fp32 -> bf16 round-to-nearest-even (bit trick, matches v_cvt rounding)
DI uint32_t f2bf(float f) {
  uint32_t u = __float_as_uint(f);
  return (u + 0x7fffu + ((u >> 16) & 1u)) >> 16;
}

DI uint32_t pk2(float a, float b) {
  return f2bf(a) | (f2bf(b) << 16);
}

DI short8 cvt8(float4 a, float4 b) {
  int4v t;
  t.x = (int)pk2(a.x, a.y);
  t.y = (int)pk2(a.z, a.w);
  t.z = (int)pk2(b.x, b.y);
  t.w = (int)pk2(b.z, b.w);
  return __builtin_bit_cast(short8, t);
}

// ---------------------------------------------------------------------------
// Convert x (64x32000) and hidden_states (2x64x1024) fp32 -> bf16 once.
__global__ __launch_bounds__(256) void convert_k(
    const float* __restrict__ x, const float* __restrict__ hs,
    ushort* __restrict__ xb, ushort* __restrict__ hb) {
  const int NX4 = 512000;   // 2048000/4
  const int NH4 = 32768;    // 131072/4
  int i = blockIdx.x * 256 + threadIdx.x;
  if (i < NX4) {
    float4 v = *(const float4*)(x + 4 * (size_t)i);
    uint2 o;
    o.x = pk2(v.x, v.y);
    o.y = pk2(v.z, v.w);
    *(uint2*)(xb + 4 * (size_t)i) = o;
  } else if (i < NX4 + NH4) {
    int j = i - NX4;
    float4 v = *(const float4*)(hs + 4 * (size_t)j);
    uint2 o;
    o.x = pk2(v.x, v.y);
    o.y = pk2(v.z, v.w);
    *(uint2*)(hb + 4 * (size_t)j) = o;
  }
}

// ---------------------------------------------------------------------------
// Gates GEMM, one gate per block (blockIdx.z): raises grid 4x, cuts VGPRs.
// zpart[chunk][b][g*1024+h] = sum_k A[b,k] * W[(g*1024+h), k] over the chunk.
__global__ __launch_bounds__(256) void gemm_gates(
    const ushort* __restrict__ A1, const float* __restrict__ W1, int K1, int nch1, int steps1,
    const ushort* __restrict__ A2, const float* __restrict__ W2, int K2, int nch2, int steps2,
    float* __restrict__ zpart) {
  const int hblk = blockIdx.x;
  const int chunk = blockIdx.y;
  const int g = blockIdx.z;
  const ushort* A;
  const float* W;
  int K, steps;
  long kbase;
  if (chunk < nch1) {
    A = A1; W = W1; K = K1; steps = steps1;
    kbase = (long)chunk * steps1 * 32;
  } else {
    A = A2; W = W2; K = K2; steps = steps2;
    kbase = (long)(chunk - nch1) * steps2 * 32;
  }
  const int tid = threadIdx.x;
  const int wv = tid >> 6;
  const int lane = tid & 63;
  const int l15 = lane & 15;
  const int l4 = lane >> 4;
  const int h = hblk * 64 + wv * 16 + l15;

  const ushort* arow[4];
#pragma unroll
  for (int m = 0; m < 4; ++m)
    arow[m] = A + (size_t)(m * 16 + l15) * K + kbase + l4 * 8;
  const float* wrow = W + (size_t)(g * 1024 + h) * K + kbase + l4 * 8;

  f32x4 acc[4];
#pragma unroll
  for (int m = 0; m < 4; ++m) acc[m] = f32x4{0.f, 0.f, 0.f, 0.f};

  for (int s = 0; s < steps; ++s) {
    short8 af[4];
#pragma unroll
    for (int m = 0; m < 4; ++m)
      af[m] = *(const short8*)(arow[m] + (size_t)s * 32);
    const float* wp = wrow + (size_t)s * 32;
    float4 w0 = *(const float4*)wp;
    float4 w1 = *(const float4*)(wp + 4);
    short8 bfr = cvt8(w0, w1);
#pragma unroll
    for (int m = 0; m < 4; ++m)
      acc[m] = mfma16(af[m], bfr, acc[m]);
  }

  // D mapping: row = l4*4 + r, col = l15
  float* zp = zpart + (size_t)chunk * (64 * 4096) + (size_t)(l4 * 4) * 4096 +
              g * 1024 + h;
#pragma unroll
  for (int m = 0; m < 4; ++m)
#pragma unroll
    for (int r = 0; r < 4; ++r)
      zp[(size_t)(m * 16 + r) * 4096] = acc[m][r];
}

// ---------------------------------------------------------------------------
// Reduce K-split partials + biases, apply LSTM cell, emit h (fp32 + bf16), c.
__global__ __launch_bounds__(256) void lstm_cell_k(
    const float* __restrict__ zpart, int nslots,
    const float* __restrict__ bx, const float* __restrict__ bhl,
    const float* __restrict__ c_in,
    float* __restrict__ h_out, float* __restrict__ c_out,
    ushort* __restrict__ h_out_b) {
  int idx = blockIdx.x * 256 + threadIdx.x;
  if (idx >= 64 * 1024) return;
  int h = idx & 1023;
  float z0 = bx[h] + bhl[h];
  float z1 = bx[1024 + h] + bhl[1024 + h];
  float z2 = bx[2048 + h] + bhl[2048 + h];
  float z3 = bx[3072 + h] + bhl[3072 + h];
  int b = idx >> 10;
  const float* zp = zpart + (size_t)b * 4096 + h;
  for (int s = 0; s < nslots; ++s) {
    const float* p = zp + (size_t)s * (64 * 4096);
    z0 += p[0];
    z1 += p[1024];
    z2 += p[2048];
    z3 += p[3072];
  }
  float f = 1.f / (1.f + expf(-z0));
  float i = 1.f / (1.f + expf(-z1));
  float o = 1.f / (1.f + expf(-z2));
  float g = tanhf(z3);
  float c = f * c_in[idx] + i * g;
  float hv = o * tanhf(c);
  h_out[idx] = hv;
  c_out[idx] = c;
  h_out_b[idx] = (ushort)f2bf(hv);
}

// ---------------------------------------------------------------------------
// Decoder GEMM: one wave per block, 16 cols per wave -> 2000 blocks.
__global__ __launch_bounds__(64) void gemm_dec(
    const ushort* __restrict__ A, const float* __restrict__ W,
    const float* __restrict__ bias, float* __restrict__ logits) {
  const int lane = threadIdx.x;
  const int l15 = lane & 15;
  const int l4 = lane >> 4;
  const int col = blockIdx.x * 16 + l15;

  const ushort* arow[4];
#pragma unroll
  for (int m = 0; m < 4; ++m)
    arow[m] = A + (size_t)(m * 16 + l15) * 1024 + l4 * 8;
  const float* wrow = W + (size_t)col * 1024 + l4 * 8;

  f32x4 acc[4];
#pragma unroll
  for (int m = 0; m < 4; ++m) acc[m] = f32x4{0.f, 0.f, 0.f, 0.f};

  for (int s = 0; s < 32; ++s) {
    short8 af[4];
#pragma unroll
    for (int m = 0; m < 4; ++m)
      af[m] = *(const short8*)(arow[m] + (size_t)s * 32);
    const float* wp = wrow + (size_t)s * 32;
    float4 w0 = *(const float4*)wp;
    float4 w1 = *(const float4*)(wp + 4);
    short8 bfr = cvt8(w0, w1);
#pragma unroll
    for (int m = 0; m < 4; ++m)
      acc[m] = mfma16(af[m], bfr, acc[m]);
  }

  float bv = bias[col];
  float* lp = logits + (size_t)(l4 * 4) * 32000 + col;
#pragma unroll
  for (int m = 0; m < 4; ++m)
#pragma unroll
    for (int r = 0; r < 4; ++r)
      lp[(size_t)(m * 16 + r) * 32000] = acc[m][r] + bv;
}

// ---------------------------------------------------------------------------
// Log-softmax stage 1: per (row, quarter) partial max + expsum -> ms[row*4+c].
__global__ __launch_bounds__(256) void softmax_part1(
    const float* __restrict__ logits, float2* __restrict__ ms) {
  const int cx = blockIdx.x;   // 0..3
  const int b = blockIdx.y;    // 0..63
  const int tid = threadIdx.x;
  const int wv = tid >> 6;
  const int lane = tid & 63;
  const float* row = logits + (size_t)b * 32000 + cx * 8000;
  __shared__ float rbuf[4];

  float m = -1e30f;
  for (int i = tid; i < 8000; i += 256) m = fmaxf(m, row[i]);
#pragma unroll
  for (int d = 1; d < 64; d <<= 1) m = fmaxf(m, __shfl_xor(m, d));
  if (lane == 0) rbuf[wv] = m;
  __syncthreads();
  m = fmaxf(fmaxf(rbuf[0], rbuf[1]), fmaxf(rbuf[2], rbuf[3]));
  __syncthreads();

  float sum = 0.f;
  for (int i = tid; i < 8000; i += 256) sum += expf((row[i] - m) * 1.25f);
#pragma unroll
  for (int d = 1; d < 64; d <<= 1) sum += __shfl_xor(sum, d);
  if (lane == 0) rbuf[wv] = sum;
  __syncthreads();
  if (tid == 0) {
    sum = rbuf[0] + rbuf[1] + rbuf[2] + rbuf[3];
    ms[b * 4 + cx] = make_float2(m, sum);
  }
}

// Log-softmax stage 2: combine partials, write logp. 8 blocks per row.
__global__ __launch_bounds__(256) void softmax_part2(
    const float* __restrict__ logits, const float2* __restrict__ ms,
    float* __restrict__ logp) {
  const int cx = blockIdx.x;   // 0..7
  const int b = blockIdx.y;    // 0..63
  const int tid = threadIdx.x;

  float2 p0 = ms[b * 4 + 0], p1 = ms[b * 4 + 1];
  float2 p2 = ms[b * 4 + 2], p3 = ms[b * 4 + 3];
  float M = fmaxf(fmaxf(p0.x, p1.x), fmaxf(p2.x, p3.x));
  float S = p0.y * expf((p0.x - M) * 1.25f) + p1.y * expf((p1.x - M) * 1.25f) +
            p2.y * expf((p2.x - M) * 1.25f) + p3.y * expf((p3.x - M) * 1.25f);
  float lse = logf(S);

  const float* row = logits + (size_t)b * 32000 + cx * 4000;
  float* op = logp + (size_t)b * 32000 + cx * 4000;
  for (int i = tid; i < 4000; i += 256)
    op[i] = (row[i] - M) * 1.25f - lse;
}

// ---------------------------------------------------------------------------
extern "C" void kernel_launch(void* const* d_in, const int* in_sizes, int n_in,
                              void* d_out, int out_size, void* d_ws, size_t ws_size,
                              hipStream_t stream) {
  const float* x    = (const float*)d_in[0];
  const float* hs   = (const float*)d_in[1];
  const float* cs   = (const float*)d_in[2];
  const float* Wh   = (const float*)d_in[3];
  const float* bh   = (const float*)d_in[4];
  const float* Wx0  = (const float*)d_in[5];
  const float* bx0  = (const float*)d_in[6];
  const float* Wx1  = (const float*)d_in[7];
  const float* bx1  = (const float*)d_in[8];
  const float* Wdec = (const float*)d_in[9];
  const float* bdec = (const float*)d_in[10];

  float* out   = (float*)d_out;
  float* logp  = out;                 // 64*32000
  float* houts = out + 2048000;       // 2*64*1024
  float* couts = out + 2179072;       // 2*64*1024

  char* ws = (char*)d_ws;
  ushort* xb     = (ushort*)ws;                                   // 4,096,000 B
  ushort* hb     = (ushort*)(ws + 4096000);                       //   262,144 B
  ushort* outb   = (ushort*)(ws + 4096000 + 262144);              //   262,144 B
  float*  logits = (float*)(ws + 4096000 + 262144 + 262144);      // 8,192,000 B
  float2* ms     = (float2*)(ws + 4096000 + 262144 + 262144 + 8192000); // 2 KiB
  float*  zpart  = (float*)(ws + 4096000 + 262144 + 262144 + 8192000 + 2048);
  const size_t fixed = 4096000ull + 262144 + 262144 + 8192000 + 2048;
  const size_t slot = (size_t)64 * 4096 * 4;  // 1 MiB per partial slot

  // K-split config, adapted to available workspace.
  int nch1 = 25, steps1 = 40;   // x-path: 25 chunks x 1280
  int l1ch = 8, l1steps = 4;    // layer-1 paths: 8 chunks x 128 each
  if (fixed + 29 * slot > ws_size) {
    nch1 = 10; steps1 = 100;
    if (fixed + 16 * slot > ws_size) {
      nch1 = 4; steps1 = 250;
      l1ch = 4; l1steps = 8;
    }
  }

  // 1) fp32 -> bf16 activations
  convert_k<<<2128, 256, 0, stream>>>(x, hs, xb, hb);

  // 2) layer 0 gates (x @ Wx0^T  +  h0 @ Wh0^T), K-split partials
  gemm_gates<<<dim3(16, nch1 + 4, 4), 256, 0, stream>>>(
      xb, Wx0, 32000, nch1, steps1,
      hb, Wh, 1024, 4, 8, zpart);

  // 3) layer 0 cell
  lstm_cell_k<<<256, 256, 0, stream>>>(zpart, nch1 + 4, bx0, bh, cs,
                                       houts, couts, outb);

  // 4) layer 1 gates (out0 @ Wx1^T + h1 @ Wh1^T)
  gemm_gates<<<dim3(16, 2 * l1ch, 4), 256, 0, stream>>>(
      outb, Wx1, 1024, l1ch, l1steps,
      hb + 65536, Wh + 4194304, 1024, l1ch, l1steps, zpart);

  // 5) layer 1 cell
  lstm_cell_k<<<256, 256, 0, stream>>>(zpart, 2 * l1ch, bx1, bh + 4096,
                                       cs + 65536, houts + 65536, couts + 65536,
                                       outb + 65536);

  // 6) decoder logits (2000 single-wave blocks)
  gemm_dec<<<2000, 64, 0, stream>>>(outb + 65536, Wdec, bdec, logits);

  // 7) log-softmax, two stages so all CUs participate
  softmax_part1<<<dim3(4, 64), 256, 0, stream>>>(logits, ms);
  softmax_part2<<<dim3(8, 64), 256, 0, stream>>>(logits, ms, logp);
}

// Round 4
// 276.336 us; speedup vs baseline: 1.2525x; 1.2525x over previous
//
#include <hip/hip_runtime.h>
#include <hip/hip_bf16.h>
#include <cstdint>

#define DI __device__ __forceinline__

typedef __attribute__((ext_vector_type(8))) short short8;
typedef __attribute__((ext_vector_type(4))) float f32x4;
typedef __attribute__((ext_vector_type(4))) int int4v;

DI f32x4 mfma16(short8 a, short8 b, f32x4 c) {
  return __builtin_amdgcn_mfma_f32_16x16x32_bf16(a, b, c, 0, 0, 0);
}

// fp32 -> bf16 round-to-nearest-even (bit trick, matches v_cvt rounding)
DI uint32_t f2bf(float f) {
  uint32_t u = __float_as_uint(f);
  return (u + 0x7fffu + ((u >> 16) & 1u)) >> 16;
}

DI uint32_t pk2(float a, float b) {
  return f2bf(a) | (f2bf(b) << 16);
}

DI short8 cvt8(float4 a, float4 b) {
  int4v t;
  t.x = (int)pk2(a.x, a.y);
  t.y = (int)pk2(a.z, a.w);
  t.z = (int)pk2(b.x, b.y);
  t.w = (int)pk2(b.z, b.w);
  return __builtin_bit_cast(short8, t);
}

// ---------------------------------------------------------------------------
// Mega gates GEMM (fp32 A, converted in-register). Covers three chunk types:
//   y < nch0        : x @ Wx0^T      (K=32000, chunk = steps0*32)
//   y < nch0+4      : h0 @ Wh[0]^T   (K=1024, 4 chunks of 256)
//   y < nch0+8      : h1 @ Wh[1]^T   (K=1024, 4 chunks of 256)
// Each block: 4 waves, wave wv owns cols [hblk*64+wv*16,+16), all 4 gates,
// all 64 batch rows in registers. Partials -> zpart[slot=y].
__global__ __launch_bounds__(256) void gates_f32(
    const float* __restrict__ x, const float* __restrict__ hs,
    const float* __restrict__ Wx0, const float* __restrict__ Wh,
    int nch0, int steps0, float* __restrict__ zpart) {
  const int y = blockIdx.y;
  const float* A;
  const float* W;
  int ldA, K, steps;
  long kbase;
  if (y < nch0) {
    A = x; ldA = 32000; W = Wx0; K = 32000; steps = steps0;
    kbase = (long)y * steps0 * 32;
  } else if (y < nch0 + 4) {
    A = hs; ldA = 1024; W = Wh; K = 1024; steps = 8;
    kbase = (long)(y - nch0) * 256;
  } else {
    A = hs + 65536; ldA = 1024; W = Wh + 4194304; K = 1024; steps = 8;
    kbase = (long)(y - nch0 - 4) * 256;
  }
  const int tid = threadIdx.x;
  const int wv = tid >> 6;
  const int lane = tid & 63;
  const int l15 = lane & 15;
  const int l4 = lane >> 4;
  const int h = blockIdx.x * 64 + wv * 16 + l15;

  const float* arow[4];
#pragma unroll
  for (int m = 0; m < 4; ++m)
    arow[m] = A + (size_t)(m * 16 + l15) * ldA + kbase + l4 * 8;
  const float* wrow[4];
#pragma unroll
  for (int g = 0; g < 4; ++g)
    wrow[g] = W + (size_t)(g * 1024 + h) * K + kbase + l4 * 8;

  f32x4 acc[4][4];
#pragma unroll
  for (int g = 0; g < 4; ++g)
#pragma unroll
    for (int m = 0; m < 4; ++m)
      acc[g][m] = f32x4{0.f, 0.f, 0.f, 0.f};

  for (int s = 0; s < steps; ++s) {
    short8 af[4];
#pragma unroll
    for (int m = 0; m < 4; ++m) {
      const float* ap = arow[m] + (size_t)s * 32;
      float4 a0 = *(const float4*)ap;
      float4 a1 = *(const float4*)(ap + 4);
      af[m] = cvt8(a0, a1);
    }
#pragma unroll
    for (int g = 0; g < 4; ++g) {
      const float* wp = wrow[g] + (size_t)s * 32;
      float4 w0 = *(const float4*)wp;
      float4 w1 = *(const float4*)(wp + 4);
      short8 bfr = cvt8(w0, w1);
#pragma unroll
      for (int m = 0; m < 4; ++m)
        acc[g][m] = mfma16(af[m], bfr, acc[g][m]);
    }
  }

  // D mapping: row = l4*4 + r (+ m*16), col = l15
  float* zp = zpart + (size_t)y * 262144 + (size_t)(l4 * 4) * 4096 + h;
#pragma unroll
  for (int g = 0; g < 4; ++g)
#pragma unroll
    for (int m = 0; m < 4; ++m)
#pragma unroll
      for (int r = 0; r < 4; ++r)
        zp[(size_t)(m * 16 + r) * 4096 + g * 1024] = acc[g][m][r];
}

// ---------------------------------------------------------------------------
// Layer-1 x-path gates GEMM (bf16 A = out0). 16 chunks of 64 -> zbase slots.
__global__ __launch_bounds__(256) void gates_b16(
    const ushort* __restrict__ A, const float* __restrict__ W,
    float* __restrict__ zbase) {
  const int chunk = blockIdx.y;
  const long kbase = (long)chunk * 64;
  const int tid = threadIdx.x;
  const int wv = tid >> 6;
  const int lane = tid & 63;
  const int l15 = lane & 15;
  const int l4 = lane >> 4;
  const int h = blockIdx.x * 64 + wv * 16 + l15;

  const ushort* arow[4];
#pragma unroll
  for (int m = 0; m < 4; ++m)
    arow[m] = A + (size_t)(m * 16 + l15) * 1024 + kbase + l4 * 8;
  const float* wrow[4];
#pragma unroll
  for (int g = 0; g < 4; ++g)
    wrow[g] = W + (size_t)(g * 1024 + h) * 1024 + kbase + l4 * 8;

  f32x4 acc[4][4];
#pragma unroll
  for (int g = 0; g < 4; ++g)
#pragma unroll
    for (int m = 0; m < 4; ++m)
      acc[g][m] = f32x4{0.f, 0.f, 0.f, 0.f};

#pragma unroll
  for (int s = 0; s < 2; ++s) {
    short8 af[4];
#pragma unroll
    for (int m = 0; m < 4; ++m)
      af[m] = *(const short8*)(arow[m] + (size_t)s * 32);
#pragma unroll
    for (int g = 0; g < 4; ++g) {
      const float* wp = wrow[g] + (size_t)s * 32;
      float4 w0 = *(const float4*)wp;
      float4 w1 = *(const float4*)(wp + 4);
      short8 bfr = cvt8(w0, w1);
#pragma unroll
      for (int m = 0; m < 4; ++m)
        acc[g][m] = mfma16(af[m], bfr, acc[g][m]);
    }
  }

  float* zp = zbase + (size_t)chunk * 262144 + (size_t)(l4 * 4) * 4096 + h;
#pragma unroll
  for (int g = 0; g < 4; ++g)
#pragma unroll
    for (int m = 0; m < 4; ++m)
#pragma unroll
      for (int r = 0; r < 4; ++r)
        zp[(size_t)(m * 16 + r) * 4096 + g * 1024] = acc[g][m][r];
}

// ---------------------------------------------------------------------------
// Reduce K-split partials + biases, apply LSTM cell, emit h (fp32 + bf16), c.
__global__ __launch_bounds__(256) void lstm_cell_k(
    const float* __restrict__ zpart, int nslots,
    const float* __restrict__ bx, const float* __restrict__ bhl,
    const float* __restrict__ c_in,
    float* __restrict__ h_out, float* __restrict__ c_out,
    ushort* __restrict__ h_out_b) {
  int idx = blockIdx.x * 256 + threadIdx.x;
  if (idx >= 64 * 1024) return;
  int h = idx & 1023;
  float z0 = bx[h] + bhl[h];
  float z1 = bx[1024 + h] + bhl[1024 + h];
  float z2 = bx[2048 + h] + bhl[2048 + h];
  float z3 = bx[3072 + h] + bhl[3072 + h];
  int b = idx >> 10;
  const float* zp = zpart + (size_t)b * 4096 + h;
  for (int s = 0; s < nslots; ++s) {
    const float* p = zp + (size_t)s * 262144;
    z0 += p[0];
    z1 += p[1024];
    z2 += p[2048];
    z3 += p[3072];
  }
  float f = 1.f / (1.f + expf(-z0));
  float i = 1.f / (1.f + expf(-z1));
  float o = 1.f / (1.f + expf(-z2));
  float g = tanhf(z3);
  float c = f * c_in[idx] + i * g;
  float hv = o * tanhf(c);
  h_out[idx] = hv;
  c_out[idx] = c;
  h_out_b[idx] = (ushort)f2bf(hv);
}

// ---------------------------------------------------------------------------
// Decoder GEMM: one wave per block, 16 cols per wave -> 2000 blocks.
__global__ __launch_bounds__(64) void gemm_dec(
    const ushort* __restrict__ A, const float* __restrict__ W,
    const float* __restrict__ bias, float* __restrict__ logits) {
  const int lane = threadIdx.x;
  const int l15 = lane & 15;
  const int l4 = lane >> 4;
  const int col = blockIdx.x * 16 + l15;

  const ushort* arow[4];
#pragma unroll
  for (int m = 0; m < 4; ++m)
    arow[m] = A + (size_t)(m * 16 + l15) * 1024 + l4 * 8;
  const float* wrow = W + (size_t)col * 1024 + l4 * 8;

  f32x4 acc[4];
#pragma unroll
  for (int m = 0; m < 4; ++m) acc[m] = f32x4{0.f, 0.f, 0.f, 0.f};

  for (int s = 0; s < 32; ++s) {
    short8 af[4];
#pragma unroll
    for (int m = 0; m < 4; ++m)
      af[m] = *(const short8*)(arow[m] + (size_t)s * 32);
    const float* wp = wrow + (size_t)s * 32;
    float4 w0 = *(const float4*)wp;
    float4 w1 = *(const float4*)(wp + 4);
    short8 bfr = cvt8(w0, w1);
#pragma unroll
    for (int m = 0; m < 4; ++m)
      acc[m] = mfma16(af[m], bfr, acc[m]);
  }

  float bv = bias[col];
  float* lp = logits + (size_t)(l4 * 4) * 32000 + col;
#pragma unroll
  for (int m = 0; m < 4; ++m)
#pragma unroll
    for (int r = 0; r < 4; ++r)
      lp[(size_t)(m * 16 + r) * 32000] = acc[m][r] + bv;
}

// ---------------------------------------------------------------------------
// Log-softmax stage 1: per (row, quarter) partial max + expsum -> ms[row*4+c].
__global__ __launch_bounds__(256) void softmax_part1(
    const float* __restrict__ logits, float2* __restrict__ ms) {
  const int cx = blockIdx.x;   // 0..3
  const int b = blockIdx.y;    // 0..63
  const int tid = threadIdx.x;
  const int wv = tid >> 6;
  const int lane = tid & 63;
  const float* row = logits + (size_t)b * 32000 + cx * 8000;
  __shared__ float rbuf[4];

  float m = -1e30f;
  for (int i = tid; i < 8000; i += 256) m = fmaxf(m, row[i]);
#pragma unroll
  for (int d = 1; d < 64; d <<= 1) m = fmaxf(m, __shfl_xor(m, d));
  if (lane == 0) rbuf[wv] = m;
  __syncthreads();
  m = fmaxf(fmaxf(rbuf[0], rbuf[1]), fmaxf(rbuf[2], rbuf[3]));
  __syncthreads();

  float sum = 0.f;
  for (int i = tid; i < 8000; i += 256) sum += expf((row[i] - m) * 1.25f);
#pragma unroll
  for (int d = 1; d < 64; d <<= 1) sum += __shfl_xor(sum, d);
  if (lane == 0) rbuf[wv] = sum;
  __syncthreads();
  if (tid == 0) {
    sum = rbuf[0] + rbuf[1] + rbuf[2] + rbuf[3];
    ms[b * 4 + cx] = make_float2(m, sum);
  }
}

// Log-softmax stage 2: combine partials, write logp. 8 blocks per row.
__global__ __launch_bounds__(256) void softmax_part2(
    const float* __restrict__ logits, const float2* __restrict__ ms,
    float* __restrict__ logp) {
  const int cx = blockIdx.x;   // 0..7
  const int b = blockIdx.y;    // 0..63
  const int tid = threadIdx.x;

  float2 p0 = ms[b * 4 + 0], p1 = ms[b * 4 + 1];
  float2 p2 = ms[b * 4 + 2], p3 = ms[b * 4 + 3];
  float M = fmaxf(fmaxf(p0.x, p1.x), fmaxf(p2.x, p3.x));
  float S = p0.y * expf((p0.x - M) * 1.25f) + p1.y * expf((p1.x - M) * 1.25f) +
            p2.y * expf((p2.x - M) * 1.25f) + p3.y * expf((p3.x - M) * 1.25f);
  float lse = logf(S);

  const float* row = logits + (size_t)b * 32000 + cx * 4000;
  float* op = logp + (size_t)b * 32000 + cx * 4000;
  for (int i = tid; i < 4000; i += 256)
    op[i] = (row[i] - M) * 1.25f - lse;
}

// ---------------------------------------------------------------------------
extern "C" void kernel_launch(void* const* d_in, const int* in_sizes, int n_in,
                              void* d_out, int out_size, void* d_ws, size_t ws_size,
                              hipStream_t stream) {
  const float* x    = (const float*)d_in[0];
  const float* hs   = (const float*)d_in[1];
  const float* cs   = (const float*)d_in[2];
  const float* Wh   = (const float*)d_in[3];
  const float* bh   = (const float*)d_in[4];
  const float* Wx0  = (const float*)d_in[5];
  const float* bx0  = (const float*)d_in[6];
  const float* Wx1  = (const float*)d_in[7];
  const float* bx1  = (const float*)d_in[8];
  const float* Wdec = (const float*)d_in[9];
  const float* bdec = (const float*)d_in[10];

  float* out   = (float*)d_out;
  float* logp  = out;                 // 64*32000
  float* houts = out + 2048000;       // 2*64*1024
  float* couts = out + 2179072;       // 2*64*1024

  char* ws = (char*)d_ws;
  ushort* outb   = (ushort*)ws;                          //   262,144 B (2 layers)
  float*  logits = (float*)(ws + 262144);                // 8,192,000 B
  float2* ms     = (float2*)(ws + 262144 + 8192000);     //     2,048 B
  float*  zpart  = (float*)(ws + 262144 + 8192000 + 2048);
  const size_t fixed = 262144ull + 8192000 + 2048;
  const size_t slot = (size_t)262144 * 4;  // 1 MiB per partial slot

  // zpart slots: [0,nch0) x-path, [nch0,nch0+4) h0-path, [nch0+4,nch0+8)
  // h1-path, [nch0+8,nch0+24) layer-1 x-path.
  int nch0 = 25, steps0 = 40;
  if (fixed + (size_t)(25 + 24) * slot > ws_size) {
    nch0 = 8; steps0 = 125;
  }

  // 1) layer-0 gates + layer-1 h-path (all input-only dependencies)
  gates_f32<<<dim3(16, nch0 + 8), 256, 0, stream>>>(
      x, hs, Wx0, Wh, nch0, steps0, zpart);

  // 2) layer-0 cell: reduce slots [0, nch0+4)
  lstm_cell_k<<<256, 256, 0, stream>>>(zpart, nch0 + 4, bx0, bh, cs,
                                       houts, couts, outb);

  // 3) layer-1 x-path gates -> slots [nch0+8, nch0+24)
  gates_b16<<<dim3(16, 16), 256, 0, stream>>>(
      outb, Wx1, zpart + (size_t)(nch0 + 8) * 262144);

  // 4) layer-1 cell: reduce slots [nch0+4, nch0+24)  (h1 partials + x-path)
  lstm_cell_k<<<256, 256, 0, stream>>>(zpart + (size_t)(nch0 + 4) * 262144, 20,
                                       bx1, bh + 4096, cs + 65536,
                                       houts + 65536, couts + 65536,
                                       outb + 65536);

  // 5) decoder logits (2000 single-wave blocks)
  gemm_dec<<<2000, 64, 0, stream>>>(outb + 65536, Wdec, bdec, logits);

  // 6) log-softmax, two stages so all CUs participate
  softmax_part1<<<dim3(4, 64), 256, 0, stream>>>(logits, ms);
  softmax_part2<<<dim3(8, 64), 256, 0, stream>>>(logits, ms, logp);
}